// Round 3
// baseline (1518.747 us; speedup 1.0000x reference)
//
#include <hip/hip_runtime.h>

#define N_NODES 50000
#define N_EDGES 800000
#define DIM 128
#define BN 32

typedef unsigned short u16;

__device__ __forceinline__ float bf2f(u16 v) {
    union { unsigned int u; float f; } x;
    x.u = ((unsigned int)v) << 16;
    return x.f;
}

__device__ __forceinline__ u16 f2bf(float f) {
    union { unsigned int u; float f; } x;
    x.f = f;
    return (u16)((x.u + 0x7FFFu + ((x.u >> 16) & 1u)) >> 16);  // RNE
}

// Dtype sniff: if h is fp32, u16[2*i] is the LOW mantissa half of float i ->
// interpreted as bf16 its exponent is ~uniform(0..255): ~65% "insane".
// If h is bf16 (N(0,1) data), u16[2*i] is a genuine value: ~0% insane.
__global__ void detect_kernel(const void* hraw, int* flag) {
    __shared__ int cnt;
    if (threadIdx.x == 0) cnt = 0;
    __syncthreads();
    const u16* p = (const u16*)hraw;
    u16 v = p[2 * threadIdx.x];
    float a = fabsf(bf2f(v));
    int insane = ((v & 0x7F80) == 0x7F80) ||           // inf/nan exponent
                 (a != 0.0f && (a > 1e6f || a < 1e-20f));
    if (insane) atomicAdd(&cnt, 1);
    __syncthreads();
    if (threadIdx.x == 0) flag[0] = (cnt > 64) ? 1 : 0;   // 1 => fp32 inputs
}

// agg[dst-lo] += h[src]*norm[src] - r[rel]; one thread per (edge, 4-dim group).
__global__ __launch_bounds__(256) void scatter_kernel(
    const void* __restrict__ h, const void* __restrict__ r, const void* __restrict__ norm,
    const int* __restrict__ src, const int* __restrict__ dst, const int* __restrict__ rel,
    float* __restrict__ agg, const int* __restrict__ flag, int lo, int hi)
{
    int gid = blockIdx.x * 256 + threadIdx.x;   // E*32 threads exactly
    int e = gid >> 5;
    int g = gid & 31;
    int t = dst[e];
    if (t < lo || t >= hi) return;
    int s = src[e], rl = rel[e];
    float nv, hx, hy, hz, hw, rx, ry, rz, rw;
    if (flag[0]) {
        const float* hf = (const float*)h;
        const float* rf = (const float*)r;
        nv = ((const float*)norm)[s];
        float4 h4 = *(const float4*)(hf + (size_t)s * DIM + g * 4);
        float4 r4 = *(const float4*)(rf + (size_t)rl * DIM + g * 4);
        hx = h4.x; hy = h4.y; hz = h4.z; hw = h4.w;
        rx = r4.x; ry = r4.y; rz = r4.z; rw = r4.w;
    } else {
        const u16* hb = (const u16*)h;
        const u16* rb = (const u16*)r;
        nv = bf2f(((const u16*)norm)[s]);
        ushort4 h4 = *(const ushort4*)(hb + (size_t)s * DIM + g * 4);
        ushort4 r4 = *(const ushort4*)(rb + (size_t)rl * DIM + g * 4);
        hx = bf2f(h4.x); hy = bf2f(h4.y); hz = bf2f(h4.z); hw = bf2f(h4.w);
        rx = bf2f(r4.x); ry = bf2f(r4.y); rz = bf2f(r4.z); rw = bf2f(r4.w);
    }
    float* ap = agg + (size_t)(t - lo) * DIM + g * 4;
    atomicAdd(ap + 0, hx * nv - rx);
    atomicAdd(ap + 1, hy * nv - ry);
    atomicAdd(ap + 2, hz * nv - rz);
    atomicAdd(ap + 3, hw * nv - rw);
}

// out[n] = relu([h*norm | norm*agg](n) @ [W ; W_msg] + b), n in [lo,hi).
__global__ __launch_bounds__(256) void gemm_kernel(
    const void* __restrict__ h, const float* __restrict__ agg, const void* __restrict__ norm,
    const void* __restrict__ W, const void* __restrict__ Wmsg, const void* __restrict__ b,
    void* __restrict__ out, const int* __restrict__ flag, int lo, int hi)
{
    __shared__ float X[256][36];   // rows padded to 36 floats: 16B-aligned b128 reads
    int tid = threadIdx.x;
    int n0 = lo + blockIdx.x * BN;
    const int isf = flag[0];

    for (int i = tid; i < BN * DIM; i += 256) {
        int nl = i >> 7;          // local node 0..31
        int k  = i & 127;         // dim
        int n  = n0 + nl;
        float v = 0.f, va = 0.f;
        if (n < hi) {
            if (isf) {
                float nv = ((const float*)norm)[n];
                v  = ((const float*)h)[(size_t)n * DIM + k] * nv;
                va = nv * agg[(size_t)(n - lo) * DIM + k];
            } else {
                float nv = bf2f(((const u16*)norm)[n]);
                v  = bf2f(((const u16*)h)[(size_t)n * DIM + k]) * nv;
                va = nv * agg[(size_t)(n - lo) * DIM + k];
            }
        }
        X[k][nl] = v;
        X[128 + k][nl] = va;
    }
    __syncthreads();

    int rg = tid >> 5;   // rows rg*4 .. rg*4+3
    int cg = tid & 31;   // cols cg*4 .. cg*4+3
    float acc[4][4] = {};

    if (isf) {
        const float* Wf = (const float*)W;
        const float* Wm = (const float*)Wmsg;
#pragma unroll 4
        for (int k = 0; k < 128; ++k) {
            float4 xv = *(const float4*)&X[k][rg * 4];
            float4 wv = *(const float4*)(Wf + (size_t)k * DIM + cg * 4);
            acc[0][0] += xv.x * wv.x; acc[0][1] += xv.x * wv.y; acc[0][2] += xv.x * wv.z; acc[0][3] += xv.x * wv.w;
            acc[1][0] += xv.y * wv.x; acc[1][1] += xv.y * wv.y; acc[1][2] += xv.y * wv.z; acc[1][3] += xv.y * wv.w;
            acc[2][0] += xv.z * wv.x; acc[2][1] += xv.z * wv.y; acc[2][2] += xv.z * wv.z; acc[2][3] += xv.z * wv.w;
            acc[3][0] += xv.w * wv.x; acc[3][1] += xv.w * wv.y; acc[3][2] += xv.w * wv.z; acc[3][3] += xv.w * wv.w;
        }
#pragma unroll 4
        for (int k = 0; k < 128; ++k) {
            float4 xv = *(const float4*)&X[128 + k][rg * 4];
            float4 wv = *(const float4*)(Wm + (size_t)k * DIM + cg * 4);
            acc[0][0] += xv.x * wv.x; acc[0][1] += xv.x * wv.y; acc[0][2] += xv.x * wv.z; acc[0][3] += xv.x * wv.w;
            acc[1][0] += xv.y * wv.x; acc[1][1] += xv.y * wv.y; acc[1][2] += xv.y * wv.z; acc[1][3] += xv.y * wv.w;
            acc[2][0] += xv.z * wv.x; acc[2][1] += xv.z * wv.y; acc[2][2] += xv.z * wv.z; acc[2][3] += xv.z * wv.w;
            acc[3][0] += xv.w * wv.x; acc[3][1] += xv.w * wv.y; acc[3][2] += xv.w * wv.z; acc[3][3] += xv.w * wv.w;
        }
    } else {
        const u16* Wb = (const u16*)W;
        const u16* Wm = (const u16*)Wmsg;
#pragma unroll 4
        for (int k = 0; k < 128; ++k) {
            float4 xv = *(const float4*)&X[k][rg * 4];
            ushort4 w4 = *(const ushort4*)(Wb + (size_t)k * DIM + cg * 4);
            float wx = bf2f(w4.x), wy = bf2f(w4.y), wz = bf2f(w4.z), ww = bf2f(w4.w);
            acc[0][0] += xv.x * wx; acc[0][1] += xv.x * wy; acc[0][2] += xv.x * wz; acc[0][3] += xv.x * ww;
            acc[1][0] += xv.y * wx; acc[1][1] += xv.y * wy; acc[1][2] += xv.y * wz; acc[1][3] += xv.y * ww;
            acc[2][0] += xv.z * wx; acc[2][1] += xv.z * wy; acc[2][2] += xv.z * wz; acc[2][3] += xv.z * ww;
            acc[3][0] += xv.w * wx; acc[3][1] += xv.w * wy; acc[3][2] += xv.w * wz; acc[3][3] += xv.w * ww;
        }
#pragma unroll 4
        for (int k = 0; k < 128; ++k) {
            float4 xv = *(const float4*)&X[128 + k][rg * 4];
            ushort4 w4 = *(const ushort4*)(Wm + (size_t)k * DIM + cg * 4);
            float wx = bf2f(w4.x), wy = bf2f(w4.y), wz = bf2f(w4.z), ww = bf2f(w4.w);
            acc[0][0] += xv.x * wx; acc[0][1] += xv.x * wy; acc[0][2] += xv.x * wz; acc[0][3] += xv.x * ww;
            acc[1][0] += xv.y * wx; acc[1][1] += xv.y * wy; acc[1][2] += xv.y * wz; acc[1][3] += xv.y * ww;
            acc[2][0] += xv.z * wx; acc[2][1] += xv.z * wy; acc[2][2] += xv.z * wz; acc[2][3] += xv.z * ww;
            acc[3][0] += xv.w * wx; acc[3][1] += xv.w * wy; acc[3][2] += xv.w * wz; acc[3][3] += xv.w * ww;
        }
    }

    int j = cg * 4;
    float bv0, bv1, bv2, bv3;
    if (isf) {
        float4 b4 = *(const float4*)((const float*)b + j);
        bv0 = b4.x; bv1 = b4.y; bv2 = b4.z; bv3 = b4.w;
    } else {
        ushort4 b4 = *(const ushort4*)((const u16*)b + j);
        bv0 = bf2f(b4.x); bv1 = bf2f(b4.y); bv2 = bf2f(b4.z); bv3 = bf2f(b4.w);
    }
#pragma unroll
    for (int i = 0; i < 4; ++i) {
        int n = n0 + rg * 4 + i;
        if (n < hi) {
            float v0 = acc[i][0] + bv0; v0 = v0 > 0.f ? v0 : 0.f;
            float v1 = acc[i][1] + bv1; v1 = v1 > 0.f ? v1 : 0.f;
            float v2 = acc[i][2] + bv2; v2 = v2 > 0.f ? v2 : 0.f;
            float v3 = acc[i][3] + bv3; v3 = v3 > 0.f ? v3 : 0.f;
            if (isf) {
                *(float4*)((float*)out + (size_t)n * DIM + j) = make_float4(v0, v1, v2, v3);
            } else {
                ushort4 o;
                o.x = f2bf(v0); o.y = f2bf(v1); o.z = f2bf(v2); o.w = f2bf(v3);
                *(ushort4*)((u16*)out + (size_t)n * DIM + j) = o;
            }
        }
    }
}

extern "C" void kernel_launch(void* const* d_in, const int* in_sizes, int n_in,
                              void* d_out, int out_size, void* d_ws, size_t ws_size,
                              hipStream_t stream) {
    const void* h    = d_in[0];
    const void* r    = d_in[1];
    const void* norm = d_in[2];
    const int* src   = (const int*)d_in[3];
    const int* dst   = (const int*)d_in[4];
    const int* rel   = (const int*)d_in[5];
    const void* Wmsg = d_in[6];
    const void* W    = d_in[7];
    const void* b    = d_in[8];

    int* flag  = (int*)d_ws;                         // 256 B reserved
    float* agg = (float*)((char*)d_ws + 256);

    // Chunk agg over nodes to fit ws; pure function of ws_size (graph-safe).
    long long ch = (long long)((ws_size - 256) / 4) / DIM;
    if (ch > N_NODES) ch = N_NODES;
    if (ch < 1) ch = 1;
    int CH = (int)ch;
    int P = (N_NODES + CH - 1) / CH;

    detect_kernel<<<1, 256, 0, stream>>>(h, flag);

    for (int p = 0; p < P; ++p) {
        int lo = p * CH;
        int hi = lo + CH; if (hi > N_NODES) hi = N_NODES;
        int cnt = hi - lo;
        hipMemsetAsync(agg, 0, (size_t)cnt * DIM * sizeof(float), stream);
        scatter_kernel<<<(N_EDGES * 32) / 256, 256, 0, stream>>>(h, r, norm, src, dst, rel, agg, flag, lo, hi);
        gemm_kernel<<<(cnt + BN - 1) / BN, 256, 0, stream>>>(h, agg, norm, W, Wmsg, b, d_out, flag, lo, hi);
    }
}

// Round 4
// 335.459 us; speedup vs baseline: 4.5274x; 4.5274x over previous
//
#include <hip/hip_runtime.h>

#define N_NODES 50000
#define N_EDGES 800000
#define DIM 128
#define BN 32

typedef unsigned short u16;

__device__ __forceinline__ float bf2f(u16 v) {
    union { unsigned int u; float f; } x;
    x.u = ((unsigned int)v) << 16;
    return x.f;
}

__device__ __forceinline__ u16 f2bf(float f) {
    union { unsigned int u; float f; } x;
    x.f = f;
    return (u16)((x.u + 0x7FFFu + ((x.u >> 16) & 1u)) >> 16);  // RNE
}

// Dtype sniff (see R2 notes): fp32 inputs -> low mantissa halves parse as
// insane bf16 exponents ~65% of the time; bf16 N(0,1) data ~0%.
__global__ void detect_kernel(const void* hraw, int* flag) {
    __shared__ int cnt;
    if (threadIdx.x == 0) cnt = 0;
    __syncthreads();
    const u16* p = (const u16*)hraw;
    u16 v = p[2 * threadIdx.x];
    float a = fabsf(bf2f(v));
    int insane = ((v & 0x7F80) == 0x7F80) || (a != 0.0f && (a > 1e6f || a < 1e-20f));
    if (insane) atomicAdd(&cnt, 1);
    __syncthreads();
    if (threadIdx.x == 0) flag[0] = (cnt > 64) ? 1 : 0;   // 1 => fp32 inputs
}

// ---------------- CSR build ----------------
__global__ __launch_bounds__(256) void hist_kernel(const int* __restrict__ dst, int* __restrict__ cnt) {
    int e = blockIdx.x * 256 + threadIdx.x;
    if (e < N_EDGES) atomicAdd(&cnt[dst[e]], 1);
}

// per-block exclusive scan of counts -> row_start (partial), block totals -> bsum
__global__ __launch_bounds__(256) void scan_blocks(const int* __restrict__ cnt,
                                                   int* __restrict__ row_start,
                                                   int* __restrict__ bsum) {
    __shared__ int sd[256];
    int t = threadIdx.x;
    int i = blockIdx.x * 256 + t;
    int c = (i < N_NODES) ? cnt[i] : 0;
    sd[t] = c;
    __syncthreads();
    for (int off = 1; off < 256; off <<= 1) {
        int v = (t >= off) ? sd[t - off] : 0;
        __syncthreads();
        sd[t] += v;
        __syncthreads();
    }
    if (i < N_NODES) row_start[i] = sd[t] - c;   // exclusive within block
    if (t == 255) bsum[blockIdx.x] = sd[255];
}

// single-block exclusive scan of block sums (in place)
__global__ __launch_bounds__(256) void scan_top(int* __restrict__ bsum, int nb) {
    __shared__ int sd[256];
    int t = threadIdx.x;
    int c = (t < nb) ? bsum[t] : 0;
    sd[t] = c;
    __syncthreads();
    for (int off = 1; off < 256; off <<= 1) {
        int v = (t >= off) ? sd[t - off] : 0;
        __syncthreads();
        sd[t] += v;
        __syncthreads();
    }
    if (t < nb) bsum[t] = sd[t] - c;
}

// add block offsets; copy to cursor; cap row_start[N] = E
__global__ __launch_bounds__(256) void scan_add(int* __restrict__ row_start,
                                                int* __restrict__ cursor,
                                                const int* __restrict__ bsum) {
    int i = blockIdx.x * 256 + threadIdx.x;
    if (i < N_NODES) {
        int v = row_start[i] + bsum[blockIdx.x];
        row_start[i] = v;
        cursor[i] = v;
    }
    if (i == 0) row_start[N_NODES] = N_EDGES;
}

__global__ __launch_bounds__(256) void fill_kernel(const int* __restrict__ dst,
                                                   int* __restrict__ cursor,
                                                   int* __restrict__ sorted) {
    int e = blockIdx.x * 256 + threadIdx.x;
    if (e < N_EDGES) {
        int pos = atomicAdd(&cursor[dst[e]], 1);
        sorted[pos] = e;
    }
}

// ---------------- gather: agg[n-lo] = sum_{e: dst=n} h[src]*norm[src] - r[rel] ----------------
// 32 lanes per node, 4 dims per lane. Edge metadata loaded lane-parallel in
// batches of 32, broadcast via shfl(width=32) -> inner loop issues only the
// coalesced 512B h-row / r-row reads + FMAs. No atomics.
__global__ __launch_bounds__(256) void gather_kernel(
    const void* __restrict__ h, const void* __restrict__ r, const void* __restrict__ norm,
    const int* __restrict__ src, const int* __restrict__ rel,
    const int* __restrict__ row_start, const int* __restrict__ sorted,
    float* __restrict__ agg, const int* __restrict__ flag, int lo, int hi)
{
    int gid = blockIdx.x * 256 + threadIdx.x;
    int n = lo + (gid >> 5);
    int g = gid & 31;
    if (n >= hi) return;
    int base = row_start[n];
    int deg  = row_start[n + 1] - base;
    float ax = 0.f, ay = 0.f, az = 0.f, aw = 0.f;

    if (flag[0]) {
        const float* hf = (const float*)h;
        const float* rf = (const float*)r;
        const float* nf = (const float*)norm;
        for (int i0 = 0; i0 < deg; i0 += 32) {
            int my = i0 + g;
            int s = 0, rl = 0; float nv = 0.f;
            if (my < deg) {
                int e = sorted[base + my];
                s = src[e]; rl = rel[e]; nv = nf[s];
            }
            int m = deg - i0; if (m > 32) m = 32;
            for (int j = 0; j < m; ++j) {
                int sj = __shfl(s, j, 32);
                int rlj = __shfl(rl, j, 32);
                float nvj = __shfl(nv, j, 32);
                float4 h4 = *(const float4*)(hf + (size_t)sj * DIM + g * 4);
                float4 r4 = *(const float4*)(rf + (size_t)rlj * DIM + g * 4);
                ax += h4.x * nvj - r4.x;
                ay += h4.y * nvj - r4.y;
                az += h4.z * nvj - r4.z;
                aw += h4.w * nvj - r4.w;
            }
        }
    } else {
        const u16* hb = (const u16*)h;
        const u16* rb = (const u16*)r;
        const u16* nb = (const u16*)norm;
        for (int i0 = 0; i0 < deg; i0 += 32) {
            int my = i0 + g;
            int s = 0, rl = 0; float nv = 0.f;
            if (my < deg) {
                int e = sorted[base + my];
                s = src[e]; rl = rel[e]; nv = bf2f(nb[s]);
            }
            int m = deg - i0; if (m > 32) m = 32;
            for (int j = 0; j < m; ++j) {
                int sj = __shfl(s, j, 32);
                int rlj = __shfl(rl, j, 32);
                float nvj = __shfl(nv, j, 32);
                ushort4 h4 = *(const ushort4*)(hb + (size_t)sj * DIM + g * 4);
                ushort4 r4 = *(const ushort4*)(rb + (size_t)rlj * DIM + g * 4);
                ax += bf2f(h4.x) * nvj - bf2f(r4.x);
                ay += bf2f(h4.y) * nvj - bf2f(r4.y);
                az += bf2f(h4.z) * nvj - bf2f(r4.z);
                aw += bf2f(h4.w) * nvj - bf2f(r4.w);
            }
        }
    }
    *(float4*)(agg + (size_t)(n - lo) * DIM + g * 4) = make_float4(ax, ay, az, aw);
}

// ---------------- fallback atomic scatter (only if ws too small for CSR) ----------------
__global__ __launch_bounds__(256) void scatter_kernel(
    const void* __restrict__ h, const void* __restrict__ r, const void* __restrict__ norm,
    const int* __restrict__ src, const int* __restrict__ dst, const int* __restrict__ rel,
    float* __restrict__ agg, const int* __restrict__ flag, int lo, int hi)
{
    int gid = blockIdx.x * 256 + threadIdx.x;
    int e = gid >> 5;
    int g = gid & 31;
    int t = dst[e];
    if (t < lo || t >= hi) return;
    int s = src[e], rl = rel[e];
    float nv, hx, hy, hz, hw, rx, ry, rz, rw;
    if (flag[0]) {
        nv = ((const float*)norm)[s];
        float4 h4 = *(const float4*)((const float*)h + (size_t)s * DIM + g * 4);
        float4 r4 = *(const float4*)((const float*)r + (size_t)rl * DIM + g * 4);
        hx = h4.x; hy = h4.y; hz = h4.z; hw = h4.w;
        rx = r4.x; ry = r4.y; rz = r4.z; rw = r4.w;
    } else {
        nv = bf2f(((const u16*)norm)[s]);
        ushort4 h4 = *(const ushort4*)((const u16*)h + (size_t)s * DIM + g * 4);
        ushort4 r4 = *(const ushort4*)((const u16*)r + (size_t)rl * DIM + g * 4);
        hx = bf2f(h4.x); hy = bf2f(h4.y); hz = bf2f(h4.z); hw = bf2f(h4.w);
        rx = bf2f(r4.x); ry = bf2f(r4.y); rz = bf2f(r4.z); rw = bf2f(r4.w);
    }
    float* ap = agg + (size_t)(t - lo) * DIM + g * 4;
    atomicAdd(ap + 0, hx * nv - rx);
    atomicAdd(ap + 1, hy * nv - ry);
    atomicAdd(ap + 2, hz * nv - rz);
    atomicAdd(ap + 3, hw * nv - rw);
}

// ---------------- fused epilogue GEMM (unchanged from R3, passed) ----------------
__global__ __launch_bounds__(256) void gemm_kernel(
    const void* __restrict__ h, const float* __restrict__ agg, const void* __restrict__ norm,
    const void* __restrict__ W, const void* __restrict__ Wmsg, const void* __restrict__ b,
    void* __restrict__ out, const int* __restrict__ flag, int lo, int hi)
{
    __shared__ float X[256][36];   // rows padded to 36 floats: 16B-aligned b128 reads
    int tid = threadIdx.x;
    int n0 = lo + blockIdx.x * BN;
    const int isf = flag[0];

    for (int i = tid; i < BN * DIM; i += 256) {
        int nl = i >> 7;
        int k  = i & 127;
        int n  = n0 + nl;
        float v = 0.f, va = 0.f;
        if (n < hi) {
            if (isf) {
                float nv = ((const float*)norm)[n];
                v  = ((const float*)h)[(size_t)n * DIM + k] * nv;
                va = nv * agg[(size_t)(n - lo) * DIM + k];
            } else {
                float nv = bf2f(((const u16*)norm)[n]);
                v  = bf2f(((const u16*)h)[(size_t)n * DIM + k]) * nv;
                va = nv * agg[(size_t)(n - lo) * DIM + k];
            }
        }
        X[k][nl] = v;
        X[128 + k][nl] = va;
    }
    __syncthreads();

    int rg = tid >> 5;
    int cg = tid & 31;
    float acc[4][4] = {};

    if (isf) {
        const float* Wf = (const float*)W;
        const float* Wm = (const float*)Wmsg;
#pragma unroll 4
        for (int k = 0; k < 128; ++k) {
            float4 xv = *(const float4*)&X[k][rg * 4];
            float4 wv = *(const float4*)(Wf + (size_t)k * DIM + cg * 4);
            acc[0][0] += xv.x * wv.x; acc[0][1] += xv.x * wv.y; acc[0][2] += xv.x * wv.z; acc[0][3] += xv.x * wv.w;
            acc[1][0] += xv.y * wv.x; acc[1][1] += xv.y * wv.y; acc[1][2] += xv.y * wv.z; acc[1][3] += xv.y * wv.w;
            acc[2][0] += xv.z * wv.x; acc[2][1] += xv.z * wv.y; acc[2][2] += xv.z * wv.z; acc[2][3] += xv.z * wv.w;
            acc[3][0] += xv.w * wv.x; acc[3][1] += xv.w * wv.y; acc[3][2] += xv.w * wv.z; acc[3][3] += xv.w * wv.w;
        }
#pragma unroll 4
        for (int k = 0; k < 128; ++k) {
            float4 xv = *(const float4*)&X[128 + k][rg * 4];
            float4 wv = *(const float4*)(Wm + (size_t)k * DIM + cg * 4);
            acc[0][0] += xv.x * wv.x; acc[0][1] += xv.x * wv.y; acc[0][2] += xv.x * wv.z; acc[0][3] += xv.x * wv.w;
            acc[1][0] += xv.y * wv.x; acc[1][1] += xv.y * wv.y; acc[1][2] += xv.y * wv.z; acc[1][3] += xv.y * wv.w;
            acc[2][0] += xv.z * wv.x; acc[2][1] += xv.z * wv.y; acc[2][2] += xv.z * wv.z; acc[2][3] += xv.z * wv.w;
            acc[3][0] += xv.w * wv.x; acc[3][1] += xv.w * wv.y; acc[3][2] += xv.w * wv.z; acc[3][3] += xv.w * wv.w;
        }
    } else {
        const u16* Wb = (const u16*)W;
        const u16* Wm = (const u16*)Wmsg;
#pragma unroll 4
        for (int k = 0; k < 128; ++k) {
            float4 xv = *(const float4*)&X[k][rg * 4];
            ushort4 w4 = *(const ushort4*)(Wb + (size_t)k * DIM + cg * 4);
            float wx = bf2f(w4.x), wy = bf2f(w4.y), wz = bf2f(w4.z), ww = bf2f(w4.w);
            acc[0][0] += xv.x * wx; acc[0][1] += xv.x * wy; acc[0][2] += xv.x * wz; acc[0][3] += xv.x * ww;
            acc[1][0] += xv.y * wx; acc[1][1] += xv.y * wy; acc[1][2] += xv.y * wz; acc[1][3] += xv.y * ww;
            acc[2][0] += xv.z * wx; acc[2][1] += xv.z * wy; acc[2][2] += xv.z * wz; acc[2][3] += xv.z * ww;
            acc[3][0] += xv.w * wx; acc[3][1] += xv.w * wy; acc[3][2] += xv.w * wz; acc[3][3] += xv.w * ww;
        }
#pragma unroll 4
        for (int k = 0; k < 128; ++k) {
            float4 xv = *(const float4*)&X[128 + k][rg * 4];
            ushort4 w4 = *(const ushort4*)(Wm + (size_t)k * DIM + cg * 4);
            float wx = bf2f(w4.x), wy = bf2f(w4.y), wz = bf2f(w4.z), ww = bf2f(w4.w);
            acc[0][0] += xv.x * wx; acc[0][1] += xv.x * wy; acc[0][2] += xv.x * wz; acc[0][3] += xv.x * ww;
            acc[1][0] += xv.y * wx; acc[1][1] += xv.y * wy; acc[1][2] += xv.y * wz; acc[1][3] += xv.y * ww;
            acc[2][0] += xv.z * wx; acc[2][1] += xv.z * wy; acc[2][2] += xv.z * wz; acc[2][3] += xv.z * ww;
            acc[3][0] += xv.w * wx; acc[3][1] += xv.w * wy; acc[3][2] += xv.w * wz; acc[3][3] += xv.w * ww;
        }
    }

    int j = cg * 4;
    float bv0, bv1, bv2, bv3;
    if (isf) {
        float4 b4 = *(const float4*)((const float*)b + j);
        bv0 = b4.x; bv1 = b4.y; bv2 = b4.z; bv3 = b4.w;
    } else {
        ushort4 b4 = *(const ushort4*)((const u16*)b + j);
        bv0 = bf2f(b4.x); bv1 = bf2f(b4.y); bv2 = bf2f(b4.z); bv3 = bf2f(b4.w);
    }
#pragma unroll
    for (int i = 0; i < 4; ++i) {
        int n = n0 + rg * 4 + i;
        if (n < hi) {
            float v0 = acc[i][0] + bv0; v0 = v0 > 0.f ? v0 : 0.f;
            float v1 = acc[i][1] + bv1; v1 = v1 > 0.f ? v1 : 0.f;
            float v2 = acc[i][2] + bv2; v2 = v2 > 0.f ? v2 : 0.f;
            float v3 = acc[i][3] + bv3; v3 = v3 > 0.f ? v3 : 0.f;
            if (isf) {
                *(float4*)((float*)out + (size_t)n * DIM + j) = make_float4(v0, v1, v2, v3);
            } else {
                ushort4 o;
                o.x = f2bf(v0); o.y = f2bf(v1); o.z = f2bf(v2); o.w = f2bf(v3);
                *(ushort4*)((u16*)out + (size_t)n * DIM + j) = o;
            }
        }
    }
}

static inline size_t alup(size_t x) { return (x + 255) & ~(size_t)255; }

extern "C" void kernel_launch(void* const* d_in, const int* in_sizes, int n_in,
                              void* d_out, int out_size, void* d_ws, size_t ws_size,
                              hipStream_t stream) {
    const void* h    = d_in[0];
    const void* r    = d_in[1];
    const void* norm = d_in[2];
    const int* src   = (const int*)d_in[3];
    const int* dst   = (const int*)d_in[4];
    const int* rel   = (const int*)d_in[5];
    const void* Wmsg = d_in[6];
    const void* W    = d_in[7];
    const void* b    = d_in[8];

    // ws layout (all offsets pure functions of ws_size -> graph-safe)
    char* p = (char*)d_ws;
    int* flag = (int*)p;                                   p += 256;
    size_t need_csr = alup(4 * (N_NODES + 1)) + alup(4 * N_NODES) + 1024 + alup(4 * N_EDGES);

    detect_kernel<<<1, 256, 0, stream>>>(h, flag);

    if (ws_size >= 256 + need_csr + (size_t)512 * 64) {
        int* row_start = (int*)p;                          p += alup(4 * (N_NODES + 1));
        int* cursor    = (int*)p;                          p += alup(4 * N_NODES);
        int* bsum      = (int*)p;                          p += 1024;
        int* sorted    = (int*)p;                          p += alup(4 * N_EDGES);
        float* agg     = (float*)p;

        long long ch = (long long)(ws_size - (size_t)(p - (char*)d_ws)) / (DIM * 4);
        if (ch > N_NODES) ch = N_NODES;
        int CH = (int)ch;
        int P = (N_NODES + CH - 1) / CH;
        const int NB = (N_NODES + 255) / 256;   // 196

        hipMemsetAsync(cursor, 0, (size_t)N_NODES * 4, stream);
        hist_kernel<<<(N_EDGES + 255) / 256, 256, 0, stream>>>(dst, cursor);
        scan_blocks<<<NB, 256, 0, stream>>>(cursor, row_start, bsum);
        scan_top<<<1, 256, 0, stream>>>(bsum, NB);
        scan_add<<<NB, 256, 0, stream>>>(row_start, cursor, bsum);
        fill_kernel<<<(N_EDGES + 255) / 256, 256, 0, stream>>>(dst, cursor, sorted);

        for (int pi = 0; pi < P; ++pi) {
            int lo = pi * CH;
            int hi = lo + CH; if (hi > N_NODES) hi = N_NODES;
            int cnt = hi - lo;
            gather_kernel<<<((cnt * 32) + 255) / 256, 256, 0, stream>>>(
                h, r, norm, src, rel, row_start, sorted, agg, flag, lo, hi);
            gemm_kernel<<<(cnt + BN - 1) / BN, 256, 0, stream>>>(
                h, agg, norm, W, Wmsg, b, d_out, flag, lo, hi);
        }
    } else {
        // tiny-ws fallback: atomic scatter, chunked
        float* agg = (float*)p;
        long long ch = (long long)(ws_size - 256) / (DIM * 4);
        if (ch > N_NODES) ch = N_NODES;
        if (ch < 1) ch = 1;
        int CH = (int)ch;
        int P = (N_NODES + CH - 1) / CH;
        for (int pi = 0; pi < P; ++pi) {
            int lo = pi * CH;
            int hi = lo + CH; if (hi > N_NODES) hi = N_NODES;
            int cnt = hi - lo;
            hipMemsetAsync(agg, 0, (size_t)cnt * DIM * 4, stream);
            scatter_kernel<<<(N_EDGES * 32) / 256, 256, 0, stream>>>(h, r, norm, src, dst, rel, agg, flag, lo, hi);
            gemm_kernel<<<(cnt + BN - 1) / BN, 256, 0, stream>>>(h, agg, norm, W, Wmsg, b, d_out, flag, lo, hi);
        }
    }
}

// Round 5
// 281.057 us; speedup vs baseline: 5.4037x; 1.1936x over previous
//
#include <hip/hip_runtime.h>

#define N_NODES 50000
#define N_EDGES 800000
#define DIM 128
#define K2 256          // concat K dimension
#define GN 64           // nodes per gemm block

typedef unsigned short u16;
typedef __attribute__((ext_vector_type(8))) short short8;   // 8 x bf16 = 4 VGPR
typedef __attribute__((ext_vector_type(4))) float f32x4;    // MFMA acc

__device__ __forceinline__ float bf2f(u16 v) {
    union { unsigned int u; float f; } x;
    x.u = ((unsigned int)v) << 16;
    return x.f;
}

__device__ __forceinline__ u16 f2bf(float f) {
    union { unsigned int u; float f; } x;
    x.f = f;
    return (u16)((x.u + 0x7FFFu + ((x.u >> 16) & 1u)) >> 16);  // RNE
}

// Dtype sniff (R2/R3-verified): fp32 inputs -> low mantissa halves parse as
// insane bf16 ~65% of the time; bf16 N(0,1) data ~0%.
__global__ void detect_kernel(const void* hraw, int* flag) {
    __shared__ int cnt;
    if (threadIdx.x == 0) cnt = 0;
    __syncthreads();
    const u16* p = (const u16*)hraw;
    u16 v = p[2 * threadIdx.x];
    float a = fabsf(bf2f(v));
    int insane = ((v & 0x7F80) == 0x7F80) || (a != 0.0f && (a > 1e6f || a < 1e-20f));
    if (insane) atomicAdd(&cnt, 1);
    __syncthreads();
    if (threadIdx.x == 0) flag[0] = (cnt > 64) ? 1 : 0;   // 1 => fp32 inputs
}

// prep: hx[n][0..127] = bf16(h[n]*norm[n]);  r_bf = bf16(r);
//       wt[j][k] = bf16( k<128 ? W[k][j] : Wmsg[k-128][j] )   (transposed concat)
#define PREP_H (N_NODES * 32)
#define PREP_R (200 * 32)
#define PREP_W 8192
__global__ __launch_bounds__(256) void prep_kernel(
    const void* __restrict__ h, const void* __restrict__ r, const void* __restrict__ norm,
    const void* __restrict__ W, const void* __restrict__ Wmsg,
    u16* __restrict__ hx, u16* __restrict__ r_bf, u16* __restrict__ wt,
    const int* __restrict__ flag)
{
    int t = blockIdx.x * 256 + threadIdx.x;
    int isf = flag[0];
    if (t < PREP_H) {
        int n = t >> 5, c = t & 31;
        float4 v; float nv;
        if (isf) {
            nv = ((const float*)norm)[n];
            v = *(const float4*)((const float*)h + (size_t)n * DIM + c * 4);
        } else {
            nv = bf2f(((const u16*)norm)[n]);
            ushort4 u = *(const ushort4*)((const u16*)h + (size_t)n * DIM + c * 4);
            v = make_float4(bf2f(u.x), bf2f(u.y), bf2f(u.z), bf2f(u.w));
        }
        ushort4 o;
        o.x = f2bf(v.x * nv); o.y = f2bf(v.y * nv); o.z = f2bf(v.z * nv); o.w = f2bf(v.w * nv);
        *(ushort4*)(hx + (size_t)n * K2 + c * 4) = o;
    } else if (t < PREP_H + PREP_R) {
        int t2 = t - PREP_H;
        int rho = t2 >> 5, c = t2 & 31;
        float4 v;
        if (isf) v = *(const float4*)((const float*)r + (size_t)rho * DIM + c * 4);
        else {
            ushort4 u = *(const ushort4*)((const u16*)r + (size_t)rho * DIM + c * 4);
            v = make_float4(bf2f(u.x), bf2f(u.y), bf2f(u.z), bf2f(u.w));
        }
        ushort4 o;
        o.x = f2bf(v.x); o.y = f2bf(v.y); o.z = f2bf(v.z); o.w = f2bf(v.w);
        *(ushort4*)(r_bf + (size_t)rho * DIM + c * 4) = o;
    } else if (t < PREP_H + PREP_R + PREP_W) {
        int t3 = t - PREP_H - PREP_R;
        int j = t3 >> 6;            // out-dim 0..127
        int k0 = (t3 & 63) * 4;     // k chunk
        ushort4 o;
        u16* op = (u16*)&o;
        for (int kk = 0; kk < 4; ++kk) {
            int k = k0 + kk;
            float wv;
            if (isf) wv = (k < 128) ? ((const float*)W)[(size_t)k * DIM + j]
                                    : ((const float*)Wmsg)[(size_t)(k - 128) * DIM + j];
            else     wv = (k < 128) ? bf2f(((const u16*)W)[(size_t)k * DIM + j])
                                    : bf2f(((const u16*)Wmsg)[(size_t)(k - 128) * DIM + j]);
            op[kk] = f2bf(wv);
        }
        *(ushort4*)(wt + (size_t)j * K2 + k0) = o;
    }
}

// ---------------- CSR build (cursor-only, int4-vectorized) ----------------
__global__ __launch_bounds__(256) void hist_kernel(const int* __restrict__ dst, int* __restrict__ cnt) {
    int i = blockIdx.x * 256 + threadIdx.x;
    if (i < N_EDGES / 4) {
        int4 d = ((const int4*)dst)[i];
        atomicAdd(&cnt[d.x], 1);
        atomicAdd(&cnt[d.y], 1);
        atomicAdd(&cnt[d.z], 1);
        atomicAdd(&cnt[d.w], 1);
    }
}

// in-place per-block exclusive scan of cursor; block totals -> bsum
__global__ __launch_bounds__(256) void scan_blocks(int* __restrict__ cursor, int* __restrict__ bsum) {
    __shared__ int sd[256];
    int t = threadIdx.x;
    int i = blockIdx.x * 256 + t;
    int c = (i < N_NODES) ? cursor[i] : 0;
    sd[t] = c;
    __syncthreads();
    for (int off = 1; off < 256; off <<= 1) {
        int v = (t >= off) ? sd[t - off] : 0;
        __syncthreads();
        sd[t] += v;
        __syncthreads();
    }
    if (i < N_NODES) cursor[i] = sd[t] - c;   // exclusive within block
    if (t == 255) bsum[blockIdx.x] = sd[255];
}

__global__ __launch_bounds__(256) void scan_top(int* __restrict__ bsum, int nb) {
    __shared__ int sd[256];
    int t = threadIdx.x;
    int c = (t < nb) ? bsum[t] : 0;
    sd[t] = c;
    __syncthreads();
    for (int off = 1; off < 256; off <<= 1) {
        int v = (t >= off) ? sd[t - off] : 0;
        __syncthreads();
        sd[t] += v;
        __syncthreads();
    }
    if (t < nb) bsum[t] = sd[t] - c;
}

__global__ __launch_bounds__(256) void scan_add(int* __restrict__ cursor, const int* __restrict__ bsum) {
    int i = blockIdx.x * 256 + threadIdx.x;
    if (i < N_NODES) cursor[i] += bsum[blockIdx.x];
}

// fill: spk[pos] = src | (rel<<16)  (src < 2^16, rel < 2^8). After this,
// cursor[n] = row_end(n), so row_start(n) = (n ? cursor[n-1] : 0).
__global__ __launch_bounds__(256) void fill_kernel(
    const int* __restrict__ dst, const int* __restrict__ src, const int* __restrict__ rel,
    int* __restrict__ cursor, int* __restrict__ spk)
{
    int i = blockIdx.x * 256 + threadIdx.x;
    if (i < N_EDGES / 4) {
        int4 d = ((const int4*)dst)[i];
        int4 s = ((const int4*)src)[i];
        int4 rl = ((const int4*)rel)[i];
        int p;
        p = atomicAdd(&cursor[d.x], 1); spk[p] = s.x | (rl.x << 16);
        p = atomicAdd(&cursor[d.y], 1); spk[p] = s.y | (rl.y << 16);
        p = atomicAdd(&cursor[d.z], 1); spk[p] = s.z | (rl.z << 16);
        p = atomicAdd(&cursor[d.w], 1); spk[p] = s.w | (rl.w << 16);
    }
}

// gather: hx[n][128+k] = bf16( norm[n] * sum_{e: dst=n} (hx[src][k] - r_bf[rel][k]) )
// 32 lanes/node, 4 dims/lane; packed edge metadata broadcast via shfl(width 32).
__global__ __launch_bounds__(256) void gather_kernel(
    u16* hx, const u16* __restrict__ r_bf, const void* __restrict__ norm,
    const int* __restrict__ cursor, const int* __restrict__ spk, const int* __restrict__ flag)
{
    int gid = blockIdx.x * 256 + threadIdx.x;
    int n = gid >> 5;
    int g = gid & 31;
    if (n >= N_NODES) return;
    int base = (n == 0) ? 0 : cursor[n - 1];
    int end = cursor[n];
    float ax = 0.f, ay = 0.f, az = 0.f, aw = 0.f;
    for (int i0 = base; i0 < end; i0 += 32) {
        int my = i0 + g;
        int pk = (my < end) ? spk[my] : 0;
        int m = end - i0; if (m > 32) m = 32;
        for (int j = 0; j < m; ++j) {
            int pj = __shfl(pk, j, 32);
            int s  = pj & 0xFFFF;
            int rl = (pj >> 16) & 0xFF;
            ushort4 hv = *(const ushort4*)(hx + (size_t)s * K2 + g * 4);
            ushort4 rv = *(const ushort4*)(r_bf + (size_t)rl * DIM + g * 4);
            ax += bf2f(hv.x) - bf2f(rv.x);
            ay += bf2f(hv.y) - bf2f(rv.y);
            az += bf2f(hv.z) - bf2f(rv.z);
            aw += bf2f(hv.w) - bf2f(rv.w);
        }
    }
    float nv = flag[0] ? ((const float*)norm)[n] : bf2f(((const u16*)norm)[n]);
    ushort4 o;
    o.x = f2bf(ax * nv); o.y = f2bf(ay * nv); o.z = f2bf(az * nv); o.w = f2bf(aw * nv);
    *(ushort4*)(hx + (size_t)n * K2 + 128 + g * 4) = o;   // upper half; disjoint from reads
}

// MFMA gemm: out = relu( X[50000x256] @ Wt^T + b ), X = hx bf16, Wt[j][k] bf16.
// Per block: 64 nodes staged to LDS (rows padded to 264 bf16 -> 2-way-max bank
// aliasing on A reads). Wave w: rows w*16..w*16+15, loops 8 col-tiles of 16.
// Layouts (HW-verified per guide §3): A[m=lane&15][k=quad*8+j];
// B[k=quad*8+j][n=lane&15]; C/D col=lane&15, row=quad*4+reg.
__global__ __launch_bounds__(256) void mfma_gemm(
    const u16* __restrict__ hx, const u16* __restrict__ wt,
    const void* __restrict__ bias, void* __restrict__ out, const int* __restrict__ flag)
{
    __shared__ u16 X[GN][264];
    int tid = threadIdx.x;
    int nblk = blockIdx.x * GN;

    for (int i = tid; i < GN * 32; i += 256) {       // 32 x 16B chunks per node
        int nl = i >> 5, c = i & 31;
        int n = nblk + nl;
        short8 v = {0, 0, 0, 0, 0, 0, 0, 0};
        if (n < N_NODES) v = *(const short8*)(hx + (size_t)n * K2 + c * 8);
        *(short8*)&X[nl][c * 8] = v;
    }
    __syncthreads();

    int w = tid >> 6, lane = tid & 63;
    int m = lane & 15, quad = lane >> 4;
    int row0 = w * 16;
    int isf = flag[0];

    short8 a[8];
#pragma unroll
    for (int kb = 0; kb < 8; ++kb)
        a[kb] = *(const short8*)&X[row0 + m][kb * 32 + quad * 8];

#pragma unroll
    for (int ct = 0; ct < 8; ++ct) {
        int n0 = ct * 16;
        f32x4 acc = {0.f, 0.f, 0.f, 0.f};
#pragma unroll
        for (int kb = 0; kb < 8; ++kb) {
            short8 bv = *(const short8*)(wt + (size_t)(n0 + m) * K2 + kb * 32 + quad * 8);
            acc = __builtin_amdgcn_mfma_f32_16x16x32_bf16(a[kb], bv, acc, 0, 0, 0);
        }
        int col = n0 + m;
        float bb = isf ? ((const float*)bias)[col] : bf2f(((const u16*)bias)[col]);
#pragma unroll
        for (int rg = 0; rg < 4; ++rg) {
            int n = nblk + row0 + quad * 4 + rg;
            if (n < N_NODES) {
                float v = acc[rg] + bb;
                v = v > 0.f ? v : 0.f;
                if (isf) ((float*)out)[(size_t)n * DIM + col] = v;
                else     ((u16*)out)[(size_t)n * DIM + col] = f2bf(v);
            }
        }
    }
}

static inline size_t alup(size_t x) { return (x + 255) & ~(size_t)255; }

extern "C" void kernel_launch(void* const* d_in, const int* in_sizes, int n_in,
                              void* d_out, int out_size, void* d_ws, size_t ws_size,
                              hipStream_t stream) {
    const void* h    = d_in[0];
    const void* r    = d_in[1];
    const void* norm = d_in[2];
    const int* src   = (const int*)d_in[3];
    const int* dst   = (const int*)d_in[4];
    const int* rel   = (const int*)d_in[5];
    const void* Wmsg = d_in[6];
    const void* W    = d_in[7];
    const void* b    = d_in[8];

    // ws layout (29.12 MB total; R4's P=1 proved ws >= 29.20 MB)
    char* p = (char*)d_ws;
    int* flag  = (int*)p;                    p += 256;
    u16* hx    = (u16*)p;                    p += alup((size_t)N_NODES * K2 * 2);   // 25.6 MB
    u16* r_bf  = (u16*)p;                    p += alup((size_t)200 * DIM * 2);      // 51.2 KB
    u16* wt    = (u16*)p;                    p += alup((size_t)DIM * K2 * 2);       // 64 KB
    int* cursor= (int*)p;                    p += alup((size_t)N_NODES * 4);        // 200 KB
    int* bsum  = (int*)p;                    p += 1024;
    int* spk   = (int*)p;                    p += alup((size_t)N_EDGES * 4);        // 3.2 MB

    const int NB = (N_NODES + 255) / 256;    // 196

    detect_kernel<<<1, 256, 0, stream>>>(h, flag);
    prep_kernel<<<(PREP_H + PREP_R + PREP_W + 255) / 256, 256, 0, stream>>>(
        h, r, norm, W, Wmsg, hx, r_bf, wt, flag);

    hipMemsetAsync(cursor, 0, (size_t)N_NODES * 4, stream);
    hist_kernel<<<(N_EDGES / 4 + 255) / 256, 256, 0, stream>>>(dst, cursor);
    scan_blocks<<<NB, 256, 0, stream>>>(cursor, bsum);
    scan_top<<<1, 256, 0, stream>>>(bsum, NB);
    scan_add<<<NB, 256, 0, stream>>>(cursor, bsum);
    fill_kernel<<<(N_EDGES / 4 + 255) / 256, 256, 0, stream>>>(dst, src, rel, cursor, spk);

    gather_kernel<<<(N_NODES * 32 + 255) / 256, 256, 0, stream>>>(hx, r_bf, norm, cursor, spk, flag);
    mfma_gemm<<<(N_NODES + GN - 1) / GN, 256, 0, stream>>>(hx, wt, b, d_out, flag);
}

// Round 6
// 256.731 us; speedup vs baseline: 5.9157x; 1.0948x over previous
//
#include <hip/hip_runtime.h>

#define N_NODES 50000
#define N_EDGES 800000
#define DIM 128
#define K2 256          // concat K dimension
#define GN 64           // nodes per gemm block

typedef unsigned short u16;
typedef __attribute__((ext_vector_type(8))) short short8;   // 8 x bf16 = 4 VGPR
typedef __attribute__((ext_vector_type(4))) float f32x4;    // MFMA acc

__device__ __forceinline__ float bf2f(u16 v) {
    union { unsigned int u; float f; } x;
    x.u = ((unsigned int)v) << 16;
    return x.f;
}

__device__ __forceinline__ u16 f2bf(float f) {
    union { unsigned int u; float f; } x;
    x.f = f;
    return (u16)((x.u + 0x7FFFu + ((x.u >> 16) & 1u)) >> 16);  // RNE
}

// Dtype sniff (R2/R3-verified): fp32 inputs -> low mantissa halves parse as
// insane bf16 ~65% of the time; bf16 N(0,1) data ~0%.
__global__ void detect_kernel(const void* hraw, int* flag) {
    __shared__ int cnt;
    if (threadIdx.x == 0) cnt = 0;
    __syncthreads();
    const u16* p = (const u16*)hraw;
    u16 v = p[2 * threadIdx.x];
    float a = fabsf(bf2f(v));
    int insane = ((v & 0x7F80) == 0x7F80) || (a != 0.0f && (a > 1e6f || a < 1e-20f));
    if (insane) atomicAdd(&cnt, 1);
    __syncthreads();
    if (threadIdx.x == 0) flag[0] = (cnt > 64) ? 1 : 0;   // 1 => fp32 inputs
}

// prep: hx[n][0..127] = bf16(h[n]*norm[n]);  r_bf = bf16(r);
//       wt[j][k] = bf16( k<128 ? W[k][j] : Wmsg[k-128][j] )   (transposed concat)
#define PREP_H (N_NODES * 32)
#define PREP_R (200 * 32)
#define PREP_W 8192
__global__ __launch_bounds__(256) void prep_kernel(
    const void* __restrict__ h, const void* __restrict__ r, const void* __restrict__ norm,
    const void* __restrict__ W, const void* __restrict__ Wmsg,
    u16* __restrict__ hx, u16* __restrict__ r_bf, u16* __restrict__ wt,
    const int* __restrict__ flag)
{
    int t = blockIdx.x * 256 + threadIdx.x;
    int isf = flag[0];
    if (t < PREP_H) {
        int n = t >> 5, c = t & 31;
        float4 v; float nv;
        if (isf) {
            nv = ((const float*)norm)[n];
            v = *(const float4*)((const float*)h + (size_t)n * DIM + c * 4);
        } else {
            nv = bf2f(((const u16*)norm)[n]);
            ushort4 u = *(const ushort4*)((const u16*)h + (size_t)n * DIM + c * 4);
            v = make_float4(bf2f(u.x), bf2f(u.y), bf2f(u.z), bf2f(u.w));
        }
        ushort4 o;
        o.x = f2bf(v.x * nv); o.y = f2bf(v.y * nv); o.z = f2bf(v.z * nv); o.w = f2bf(v.w * nv);
        *(ushort4*)(hx + (size_t)n * K2 + c * 4) = o;
    } else if (t < PREP_H + PREP_R) {
        int t2 = t - PREP_H;
        int rho = t2 >> 5, c = t2 & 31;
        float4 v;
        if (isf) v = *(const float4*)((const float*)r + (size_t)rho * DIM + c * 4);
        else {
            ushort4 u = *(const ushort4*)((const u16*)r + (size_t)rho * DIM + c * 4);
            v = make_float4(bf2f(u.x), bf2f(u.y), bf2f(u.z), bf2f(u.w));
        }
        ushort4 o;
        o.x = f2bf(v.x); o.y = f2bf(v.y); o.z = f2bf(v.z); o.w = f2bf(v.w);
        *(ushort4*)(r_bf + (size_t)rho * DIM + c * 4) = o;
    } else if (t < PREP_H + PREP_R + PREP_W) {
        int t3 = t - PREP_H - PREP_R;
        int j = t3 >> 6;            // out-dim 0..127
        int k0 = (t3 & 63) * 4;     // k chunk
        ushort4 o;
        u16* op = (u16*)&o;
        for (int kk = 0; kk < 4; ++kk) {
            int k = k0 + kk;
            float wv;
            if (isf) wv = (k < 128) ? ((const float*)W)[(size_t)k * DIM + j]
                                    : ((const float*)Wmsg)[(size_t)(k - 128) * DIM + j];
            else     wv = (k < 128) ? bf2f(((const u16*)W)[(size_t)k * DIM + j])
                                    : bf2f(((const u16*)Wmsg)[(size_t)(k - 128) * DIM + j]);
            op[kk] = f2bf(wv);
        }
        *(ushort4*)(wt + (size_t)j * K2 + k0) = o;
    }
}

// ---------------- CSR build ----------------
// 1 edge/thread: 3125 blocks -> ~48 waves/CU queued, hides ~900cy memory-side
// atomic latency (R5's int4 version had only 781 blocks -> 28% occupancy, 60us).
__global__ __launch_bounds__(256) void hist_kernel(const int* __restrict__ dst, int* __restrict__ cnt) {
    int e = blockIdx.x * 256 + threadIdx.x;
    if (e < N_EDGES) atomicAdd(&cnt[dst[e]], 1);
}

// in-place per-block exclusive scan of cursor; block totals -> bsum
__global__ __launch_bounds__(256) void scan_blocks(int* __restrict__ cursor, int* __restrict__ bsum) {
    __shared__ int sd[256];
    int t = threadIdx.x;
    int i = blockIdx.x * 256 + t;
    int c = (i < N_NODES) ? cursor[i] : 0;
    sd[t] = c;
    __syncthreads();
    for (int off = 1; off < 256; off <<= 1) {
        int v = (t >= off) ? sd[t - off] : 0;
        __syncthreads();
        sd[t] += v;
        __syncthreads();
    }
    if (i < N_NODES) cursor[i] = sd[t] - c;   // exclusive within block
    if (t == 255) bsum[blockIdx.x] = sd[255];
}

// fused top-scan + add: each block reduces bsum[0..blockIdx) in LDS (NB<=256)
__global__ __launch_bounds__(256) void scan_add(int* __restrict__ cursor, const int* __restrict__ bsum, int nb) {
    __shared__ int sd[256];
    int t = threadIdx.x;
    sd[t] = (t < (int)blockIdx.x && t < nb) ? bsum[t] : 0;
    __syncthreads();
    for (int off = 128; off; off >>= 1) {
        if (t < off) sd[t] += sd[t + off];
        __syncthreads();
    }
    int prefix = sd[0];
    int i = blockIdx.x * 256 + t;
    if (i < N_NODES) cursor[i] += prefix;
}

// fill: spk[pos] = src | (rel<<16). After this, cursor[n] = row_end(n),
// row_start(n) = (n ? cursor[n-1] : 0). 1 edge/thread for max TLP.
__global__ __launch_bounds__(256) void fill_kernel(
    const int* __restrict__ dst, const int* __restrict__ src, const int* __restrict__ rel,
    int* __restrict__ cursor, int* __restrict__ spk)
{
    int e = blockIdx.x * 256 + threadIdx.x;
    if (e < N_EDGES) {
        int d = dst[e];
        int s = src[e];
        int rl = rel[e];
        int pos = atomicAdd(&cursor[d], 1);
        spk[pos] = s | (rl << 16);
    }
}

// gather: hx[n][128+k] = bf16( norm[n] * sum_{e: dst=n} (hx[src][k] - r_bf[rel][k]) )
// 16 lanes/node, 8 dims/lane (b128 loads); metadata batches of 16 via shfl
// width 16; inner loop 2-edge pipelined -> 4 outstanding b128 loads.
__global__ __launch_bounds__(256) void gather_kernel(
    u16* hx, const u16* __restrict__ r_bf, const void* __restrict__ norm,
    const int* __restrict__ cursor, const int* __restrict__ spk, const int* __restrict__ flag)
{
    int gid = blockIdx.x * 256 + threadIdx.x;
    int n = gid >> 4;
    int g = gid & 15;
    if (n >= N_NODES) return;
    int base = (n == 0) ? 0 : cursor[n - 1];
    int end = cursor[n];
    float acc[8] = {};
    for (int i0 = base; i0 < end; i0 += 16) {
        int my = i0 + g;
        int pk = (my < end) ? spk[my] : 0;
        int m = end - i0; if (m > 16) m = 16;
        int j = 0;
        for (; j + 1 < m; j += 2) {
            int pj0 = __shfl(pk, j, 16);
            int pj1 = __shfl(pk, j + 1, 16);
            int s0 = pj0 & 0xFFFF, r0 = (pj0 >> 16) & 0xFF;
            int s1 = pj1 & 0xFFFF, r1 = (pj1 >> 16) & 0xFF;
            short8 h0 = *(const short8*)(hx + (size_t)s0 * K2 + g * 8);
            short8 v0 = *(const short8*)(r_bf + (size_t)r0 * DIM + g * 8);
            short8 h1 = *(const short8*)(hx + (size_t)s1 * K2 + g * 8);
            short8 v1 = *(const short8*)(r_bf + (size_t)r1 * DIM + g * 8);
#pragma unroll
            for (int d = 0; d < 8; ++d)
                acc[d] += bf2f((u16)h0[d]) - bf2f((u16)v0[d]);
#pragma unroll
            for (int d = 0; d < 8; ++d)
                acc[d] += bf2f((u16)h1[d]) - bf2f((u16)v1[d]);
        }
        if (j < m) {
            int pj = __shfl(pk, j, 16);
            int s = pj & 0xFFFF, rl = (pj >> 16) & 0xFF;
            short8 hv = *(const short8*)(hx + (size_t)s * K2 + g * 8);
            short8 rv = *(const short8*)(r_bf + (size_t)rl * DIM + g * 8);
#pragma unroll
            for (int d = 0; d < 8; ++d)
                acc[d] += bf2f((u16)hv[d]) - bf2f((u16)rv[d]);
        }
    }
    float nv = flag[0] ? ((const float*)norm)[n] : bf2f(((const u16*)norm)[n]);
    short8 o;
#pragma unroll
    for (int d = 0; d < 8; ++d) o[d] = (short)f2bf(acc[d] * nv);
    *(short8*)(hx + (size_t)n * K2 + 128 + g * 8) = o;   // upper half; disjoint from reads
}

// MFMA gemm: out = relu( X[50000x256] @ Wt^T + b ), X = hx bf16, Wt[j][k] bf16.
// Layouts (HW-verified per guide §3): A[m=lane&15][k=quad*8+j];
// B[k=quad*8+j][n=lane&15]; C/D col=lane&15, row=quad*4+reg.
__global__ __launch_bounds__(256) void mfma_gemm(
    const u16* __restrict__ hx, const u16* __restrict__ wt,
    const void* __restrict__ bias, void* __restrict__ out, const int* __restrict__ flag)
{
    __shared__ u16 X[GN][264];
    int tid = threadIdx.x;
    int nblk = blockIdx.x * GN;

    for (int i = tid; i < GN * 32; i += 256) {       // 32 x 16B chunks per node
        int nl = i >> 5, c = i & 31;
        int n = nblk + nl;
        short8 v = {0, 0, 0, 0, 0, 0, 0, 0};
        if (n < N_NODES) v = *(const short8*)(hx + (size_t)n * K2 + c * 8);
        *(short8*)&X[nl][c * 8] = v;
    }
    __syncthreads();

    int w = tid >> 6, lane = tid & 63;
    int m = lane & 15, quad = lane >> 4;
    int row0 = w * 16;
    int isf = flag[0];

    short8 a[8];
#pragma unroll
    for (int kb = 0; kb < 8; ++kb)
        a[kb] = *(const short8*)&X[row0 + m][kb * 32 + quad * 8];

#pragma unroll
    for (int ct = 0; ct < 8; ++ct) {
        int n0 = ct * 16;
        f32x4 acc = {0.f, 0.f, 0.f, 0.f};
#pragma unroll
        for (int kb = 0; kb < 8; ++kb) {
            short8 bv = *(const short8*)(wt + (size_t)(n0 + m) * K2 + kb * 32 + quad * 8);
            acc = __builtin_amdgcn_mfma_f32_16x16x32_bf16(a[kb], bv, acc, 0, 0, 0);
        }
        int col = n0 + m;
        float bb = isf ? ((const float*)bias)[col] : bf2f(((const u16*)bias)[col]);
#pragma unroll
        for (int rg = 0; rg < 4; ++rg) {
            int n = nblk + row0 + quad * 4 + rg;
            if (n < N_NODES) {
                float v = acc[rg] + bb;
                v = v > 0.f ? v : 0.f;
                if (isf) ((float*)out)[(size_t)n * DIM + col] = v;
                else     ((u16*)out)[(size_t)n * DIM + col] = f2bf(v);
            }
        }
    }
}

static inline size_t alup(size_t x) { return (x + 255) & ~(size_t)255; }

extern "C" void kernel_launch(void* const* d_in, const int* in_sizes, int n_in,
                              void* d_out, int out_size, void* d_ws, size_t ws_size,
                              hipStream_t stream) {
    const void* h    = d_in[0];
    const void* r    = d_in[1];
    const void* norm = d_in[2];
    const int* src   = (const int*)d_in[3];
    const int* dst   = (const int*)d_in[4];
    const int* rel   = (const int*)d_in[5];
    const void* Wmsg = d_in[6];
    const void* W    = d_in[7];
    const void* b    = d_in[8];

    // ws layout (29.12 MB total; R4's P=1 proved ws >= 29.20 MB)
    char* p = (char*)d_ws;
    int* flag  = (int*)p;                    p += 256;
    u16* hx    = (u16*)p;                    p += alup((size_t)N_NODES * K2 * 2);   // 25.6 MB
    u16* r_bf  = (u16*)p;                    p += alup((size_t)200 * DIM * 2);      // 51.2 KB
    u16* wt    = (u16*)p;                    p += alup((size_t)DIM * K2 * 2);       // 64 KB
    int* cursor= (int*)p;                    p += alup((size_t)N_NODES * 4);        // 200 KB
    int* bsum  = (int*)p;                    p += 1024;
    int* spk   = (int*)p;                    p += alup((size_t)N_EDGES * 4);        // 3.2 MB

    const int NB = (N_NODES + 255) / 256;    // 196
    const int EB = (N_EDGES + 255) / 256;    // 3125

    detect_kernel<<<1, 256, 0, stream>>>(h, flag);
    prep_kernel<<<(PREP_H + PREP_R + PREP_W + 255) / 256, 256, 0, stream>>>(
        h, r, norm, W, Wmsg, hx, r_bf, wt, flag);

    hipMemsetAsync(cursor, 0, (size_t)N_NODES * 4, stream);
    hist_kernel<<<EB, 256, 0, stream>>>(dst, cursor);
    scan_blocks<<<NB, 256, 0, stream>>>(cursor, bsum);
    scan_add<<<NB, 256, 0, stream>>>(cursor, bsum, NB);
    fill_kernel<<<EB, 256, 0, stream>>>(dst, src, rel, cursor, spk);

    gather_kernel<<<(N_NODES * 16 + 255) / 256, 256, 0, stream>>>(hx, r_bf, norm, cursor, spk, flag);
    mfma_gemm<<<(N_NODES + GN - 1) / GN, 256, 0, stream>>>(hx, wt, b, d_out, flag);
}

// Round 7
// 198.355 us; speedup vs baseline: 7.6567x; 1.2943x over previous
//
#include <hip/hip_runtime.h>

#define N_NODES 50000
#define N_EDGES 800000
#define DIM 128
#define K2 256          // concat K dimension
#define GN 64           // nodes per gemm block
#define NBUCK 196       // node buckets of 256 (49999>>8 = 195)
#define EPB 4096        // edges per fill_lds block
#define BCAP 16384      // max edges per bucket (mean 4082, sigma ~64)

typedef unsigned short u16;
typedef __attribute__((ext_vector_type(8))) short short8;   // 8 x bf16 = 4 VGPR
typedef __attribute__((ext_vector_type(4))) float f32x4;    // MFMA acc

__device__ __forceinline__ float bf2f(u16 v) {
    union { unsigned int u; float f; } x;
    x.u = ((unsigned int)v) << 16;
    return x.f;
}

__device__ __forceinline__ u16 f2bf(float f) {
    union { unsigned int u; float f; } x;
    x.f = f;
    return (u16)((x.u + 0x7FFFu + ((x.u >> 16) & 1u)) >> 16);  // RNE
}

// Dtype sniff (R2/R3-verified): fp32 inputs -> low mantissa halves parse as
// insane bf16 ~65% of the time; bf16 N(0,1) data ~0%.
__global__ void detect_kernel(const void* hraw, int* flag) {
    __shared__ int cnt;
    if (threadIdx.x == 0) cnt = 0;
    __syncthreads();
    const u16* p = (const u16*)hraw;
    u16 v = p[2 * threadIdx.x];
    float a = fabsf(bf2f(v));
    int insane = ((v & 0x7F80) == 0x7F80) || (a != 0.0f && (a > 1e6f || a < 1e-20f));
    if (insane) atomicAdd(&cnt, 1);
    __syncthreads();
    if (threadIdx.x == 0) flag[0] = (cnt > 64) ? 1 : 0;   // 1 => fp32 inputs
}

// prep: hx[n][0..127] = bf16(h[n]*norm[n]);  r_bf = bf16(r);
//       wt[j][k] = bf16( k<128 ? W[k][j] : Wmsg[k-128][j] )
#define PREP_H (N_NODES * 32)
#define PREP_R (200 * 32)
#define PREP_W 8192
__global__ __launch_bounds__(256) void prep_kernel(
    const void* __restrict__ h, const void* __restrict__ r, const void* __restrict__ norm,
    const void* __restrict__ W, const void* __restrict__ Wmsg,
    u16* __restrict__ hx, u16* __restrict__ r_bf, u16* __restrict__ wt,
    const int* __restrict__ flag)
{
    int t = blockIdx.x * 256 + threadIdx.x;
    int isf = flag[0];
    if (t < PREP_H) {
        int n = t >> 5, c = t & 31;
        float4 v; float nv;
        if (isf) {
            nv = ((const float*)norm)[n];
            v = *(const float4*)((const float*)h + (size_t)n * DIM + c * 4);
        } else {
            nv = bf2f(((const u16*)norm)[n]);
            ushort4 u = *(const ushort4*)((const u16*)h + (size_t)n * DIM + c * 4);
            v = make_float4(bf2f(u.x), bf2f(u.y), bf2f(u.z), bf2f(u.w));
        }
        ushort4 o;
        o.x = f2bf(v.x * nv); o.y = f2bf(v.y * nv); o.z = f2bf(v.z * nv); o.w = f2bf(v.w * nv);
        *(ushort4*)(hx + (size_t)n * K2 + c * 4) = o;
    } else if (t < PREP_H + PREP_R) {
        int t2 = t - PREP_H;
        int rho = t2 >> 5, c = t2 & 31;
        float4 v;
        if (isf) v = *(const float4*)((const float*)r + (size_t)rho * DIM + c * 4);
        else {
            ushort4 u = *(const ushort4*)((const u16*)r + (size_t)rho * DIM + c * 4);
            v = make_float4(bf2f(u.x), bf2f(u.y), bf2f(u.z), bf2f(u.w));
        }
        ushort4 o;
        o.x = f2bf(v.x); o.y = f2bf(v.y); o.z = f2bf(v.z); o.w = f2bf(v.w);
        *(ushort4*)(r_bf + (size_t)rho * DIM + c * 4) = o;
    } else if (t < PREP_H + PREP_R + PREP_W) {
        int t3 = t - PREP_H - PREP_R;
        int j = t3 >> 6;
        int k0 = (t3 & 63) * 4;
        ushort4 o;
        u16* op = (u16*)&o;
        for (int kk = 0; kk < 4; ++kk) {
            int k = k0 + kk;
            float wv;
            if (isf) wv = (k < 128) ? ((const float*)W)[(size_t)k * DIM + j]
                                    : ((const float*)Wmsg)[(size_t)(k - 128) * DIM + j];
            else     wv = (k < 128) ? bf2f(((const u16*)W)[(size_t)k * DIM + j])
                                    : bf2f(((const u16*)Wmsg)[(size_t)(k - 128) * DIM + j]);
            op[kk] = f2bf(wv);
        }
        *(ushort4*)(wt + (size_t)j * K2 + k0) = o;
    }
}

// ---------------- CSR build, write-amplification-free ----------------
// coarse histogram over 196 dst-buckets, LDS pre-aggregated
__global__ __launch_bounds__(256) void coarse_hist(const int* __restrict__ dst, int* __restrict__ bucketCount) {
    __shared__ int hh[NBUCK];
    for (int i = threadIdx.x; i < NBUCK; i += 256) hh[i] = 0;
    __syncthreads();
    int stride = gridDim.x * 256;
    for (int e = blockIdx.x * 256 + threadIdx.x; e < N_EDGES; e += stride)
        atomicAdd(&hh[dst[e] >> 8], 1);
    __syncthreads();
    for (int i = threadIdx.x; i < NBUCK; i += 256)
        if (hh[i]) atomicAdd(&bucketCount[i], hh[i]);
}

// exclusive scan of 196 bucket counts -> bucketBase[197]; cursor copy
__global__ void bucket_scan(const int* __restrict__ bucketCount,
                            int* __restrict__ bucketBase, int* __restrict__ bucketCursor) {
    __shared__ int sd[256];
    int t = threadIdx.x;
    int c = (t < NBUCK) ? bucketCount[t] : 0;
    sd[t] = c;
    __syncthreads();
    for (int off = 1; off < 256; off <<= 1) {
        int v = (t >= off) ? sd[t - off] : 0;
        __syncthreads();
        sd[t] += v;
        __syncthreads();
    }
    if (t < NBUCK) { int ex = sd[t] - c; bucketBase[t] = ex; bucketCursor[t] = ex; }
    if (t == 0) bucketBase[NBUCK] = N_EDGES;
}

// bucket-scatter with LDS pre-sort: each block sorts EPB edges by bucket in
// LDS, claims per-bucket global ranges once, then writes out LINEARLY ->
// consecutive threads hit consecutive addresses (runs of ~21 edges/bucket).
// payload = src | rel<<16 | (dst&255)<<24
__global__ __launch_bounds__(512) void fill_lds(
    const int* __restrict__ dst, const int* __restrict__ src, const int* __restrict__ rel,
    int* __restrict__ bucketCursor, int* __restrict__ spk)
{
    __shared__ int hist[NBUCK];
    __shared__ int lbase[NBUCK];
    __shared__ int gbase[NBUCK];
    __shared__ int sd[256];
    __shared__ int pay[EPB];
    __shared__ unsigned char bkt[EPB];
    int tid = threadIdx.x;
    for (int i = tid; i < NBUCK; i += 512) hist[i] = 0;
    __syncthreads();
    int e0 = blockIdx.x * EPB;
    int myb[8], myr[8], myp[8];
#pragma unroll
    for (int i = 0; i < 8; ++i) {
        int e = e0 + i * 512 + tid;
        myb[i] = -1;
        if (e < N_EDGES) {
            int d = dst[e];
            int b = d >> 8;
            myb[i] = b;
            myr[i] = atomicAdd(&hist[b], 1);
            myp[i] = src[e] | (rel[e] << 16) | ((d & 255) << 24);
        }
    }
    __syncthreads();
    if (tid < 256) sd[tid] = (tid < NBUCK) ? hist[tid] : 0;
    __syncthreads();
    for (int off = 1; off < 256; off <<= 1) {
        int v = 0;
        if (tid < 256 && tid >= off) v = sd[tid - off];
        __syncthreads();
        if (tid < 256) sd[tid] += v;
        __syncthreads();
    }
    if (tid < NBUCK) {
        lbase[tid] = sd[tid] - hist[tid];
        gbase[tid] = hist[tid] ? atomicAdd(&bucketCursor[tid], hist[tid]) : 0;
    }
    __syncthreads();
#pragma unroll
    for (int i = 0; i < 8; ++i) {
        if (myb[i] >= 0) {
            int lp = lbase[myb[i]] + myr[i];
            pay[lp] = myp[i];
            bkt[lp] = (unsigned char)myb[i];
        }
    }
    __syncthreads();
    int total = N_EDGES - e0; if (total > EPB) total = EPB;
#pragma unroll
    for (int i = 0; i < 8; ++i) {
        int lp = i * 512 + tid;
        if (lp < total) {
            int b = bkt[lp];
            spk[gbase[b] + (lp - lbase[b])] = pay[lp];
        }
    }
}

// per-bucket counting sort by dst&255, IN-PLACE via 64KB LDS staging. Writes
// land in the block-owned region -> lines fully dirty -> no HBM amplification.
// Also emits cursor[n] = row_end(n), replacing the old node scans.
__global__ __launch_bounds__(256) void node_sort(
    const int* __restrict__ bucketBase, int* __restrict__ spk, int* __restrict__ cursor)
{
    __shared__ int stage[BCAP];
    __shared__ int hist[256];
    __shared__ int nbase[256];
    __shared__ int sd[256];
    int b = blockIdx.x;
    int base = bucketBase[b], end = bucketBase[b + 1];
    int size = end - base; if (size > BCAP) size = BCAP;
    int t = threadIdx.x;
    hist[t] = 0;
    __syncthreads();
    for (int i = t; i < size; i += 256) {
        int pk = spk[base + i];
        stage[i] = pk;
        atomicAdd(&hist[(pk >> 24) & 255], 1);
    }
    __syncthreads();
    int c = hist[t];
    sd[t] = c;
    __syncthreads();
    for (int off = 1; off < 256; off <<= 1) {
        int v = (t >= off) ? sd[t - off] : 0;
        __syncthreads();
        sd[t] += v;
        __syncthreads();
    }
    nbase[t] = sd[t] - c;                 // exclusive
    int node = b * 256 + t;
    if (node < N_NODES) cursor[node] = base + sd[t];   // row_end (inclusive)
    hist[t] = 0;                          // reuse as rank counters
    __syncthreads();
    for (int i = t; i < size; i += 256) {
        int pk = stage[i];
        int nd = (pk >> 24) & 255;
        int rk = atomicAdd(&hist[nd], 1);
        spk[base + nbase[nd] + rk] = pk;
    }
}

// gather: hx[n][128+k] = bf16( norm[n] * sum_{e: dst=n} (hx[src][k] - r_bf[rel][k]) )
// 16 lanes/node, 8 dims/lane (b128 loads); metadata via shfl width 16.
__global__ __launch_bounds__(256) void gather_kernel(
    u16* hx, const u16* __restrict__ r_bf, const void* __restrict__ norm,
    const int* __restrict__ cursor, const int* __restrict__ spk, const int* __restrict__ flag)
{
    int gid = blockIdx.x * 256 + threadIdx.x;
    int n = gid >> 4;
    int g = gid & 15;
    if (n >= N_NODES) return;
    int base = (n == 0) ? 0 : cursor[n - 1];
    int end = cursor[n];
    float acc[8] = {};
    for (int i0 = base; i0 < end; i0 += 16) {
        int my = i0 + g;
        int pk = (my < end) ? spk[my] : 0;
        int m = end - i0; if (m > 16) m = 16;
        int j = 0;
        for (; j + 1 < m; j += 2) {
            int pj0 = __shfl(pk, j, 16);
            int pj1 = __shfl(pk, j + 1, 16);
            int s0 = pj0 & 0xFFFF, r0 = (pj0 >> 16) & 0xFF;
            int s1 = pj1 & 0xFFFF, r1 = (pj1 >> 16) & 0xFF;
            short8 h0 = *(const short8*)(hx + (size_t)s0 * K2 + g * 8);
            short8 v0 = *(const short8*)(r_bf + (size_t)r0 * DIM + g * 8);
            short8 h1 = *(const short8*)(hx + (size_t)s1 * K2 + g * 8);
            short8 v1 = *(const short8*)(r_bf + (size_t)r1 * DIM + g * 8);
#pragma unroll
            for (int d = 0; d < 8; ++d)
                acc[d] += bf2f((u16)h0[d]) - bf2f((u16)v0[d]);
#pragma unroll
            for (int d = 0; d < 8; ++d)
                acc[d] += bf2f((u16)h1[d]) - bf2f((u16)v1[d]);
        }
        if (j < m) {
            int pj = __shfl(pk, j, 16);
            int s = pj & 0xFFFF, rl = (pj >> 16) & 0xFF;
            short8 hv = *(const short8*)(hx + (size_t)s * K2 + g * 8);
            short8 rv = *(const short8*)(r_bf + (size_t)rl * DIM + g * 8);
#pragma unroll
            for (int d = 0; d < 8; ++d)
                acc[d] += bf2f((u16)hv[d]) - bf2f((u16)rv[d]);
        }
    }
    float nv = flag[0] ? ((const float*)norm)[n] : bf2f(((const u16*)norm)[n]);
    short8 o;
#pragma unroll
    for (int d = 0; d < 8; ++d) o[d] = (short)f2bf(acc[d] * nv);
    *(short8*)(hx + (size_t)n * K2 + 128 + g * 8) = o;
}

// MFMA gemm: out = relu( X[50000x256] @ Wt^T + b ). Layouts per guide §3.
__global__ __launch_bounds__(256) void mfma_gemm(
    const u16* __restrict__ hx, const u16* __restrict__ wt,
    const void* __restrict__ bias, void* __restrict__ out, const int* __restrict__ flag)
{
    __shared__ u16 X[GN][264];
    int tid = threadIdx.x;
    int nblk = blockIdx.x * GN;

    for (int i = tid; i < GN * 32; i += 256) {
        int nl = i >> 5, c = i & 31;
        int n = nblk + nl;
        short8 v = {0, 0, 0, 0, 0, 0, 0, 0};
        if (n < N_NODES) v = *(const short8*)(hx + (size_t)n * K2 + c * 8);
        *(short8*)&X[nl][c * 8] = v;
    }
    __syncthreads();

    int w = tid >> 6, lane = tid & 63;
    int m = lane & 15, quad = lane >> 4;
    int row0 = w * 16;
    int isf = flag[0];

    short8 a[8];
#pragma unroll
    for (int kb = 0; kb < 8; ++kb)
        a[kb] = *(const short8*)&X[row0 + m][kb * 32 + quad * 8];

#pragma unroll
    for (int ct = 0; ct < 8; ++ct) {
        int n0 = ct * 16;
        f32x4 acc = {0.f, 0.f, 0.f, 0.f};
#pragma unroll
        for (int kb = 0; kb < 8; ++kb) {
            short8 bv = *(const short8*)(wt + (size_t)(n0 + m) * K2 + kb * 32 + quad * 8);
            acc = __builtin_amdgcn_mfma_f32_16x16x32_bf16(a[kb], bv, acc, 0, 0, 0);
        }
        int col = n0 + m;
        float bb = isf ? ((const float*)bias)[col] : bf2f(((const u16*)bias)[col]);
#pragma unroll
        for (int rg = 0; rg < 4; ++rg) {
            int n = nblk + row0 + quad * 4 + rg;
            if (n < N_NODES) {
                float v = acc[rg] + bb;
                v = v > 0.f ? v : 0.f;
                if (isf) ((float*)out)[(size_t)n * DIM + col] = v;
                else     ((u16*)out)[(size_t)n * DIM + col] = f2bf(v);
            }
        }
    }
}

static inline size_t alup(size_t x) { return (x + 255) & ~(size_t)255; }

extern "C" void kernel_launch(void* const* d_in, const int* in_sizes, int n_in,
                              void* d_out, int out_size, void* d_ws, size_t ws_size,
                              hipStream_t stream) {
    const void* h    = d_in[0];
    const void* r    = d_in[1];
    const void* norm = d_in[2];
    const int* src   = (const int*)d_in[3];
    const int* dst   = (const int*)d_in[4];
    const int* rel   = (const int*)d_in[5];
    const void* Wmsg = d_in[6];
    const void* W    = d_in[7];
    const void* b    = d_in[8];

    // ws layout (~29.1 MB; proven ws >= 29.2 MB from R4's P=1)
    char* p = (char*)d_ws;
    int* flag     = (int*)p;                 p += 256;
    u16* hx       = (u16*)p;                 p += alup((size_t)N_NODES * K2 * 2);   // 25.6 MB
    u16* r_bf     = (u16*)p;                 p += alup((size_t)200 * DIM * 2);
    u16* wt       = (u16*)p;                 p += alup((size_t)DIM * K2 * 2);
    int* cursor   = (int*)p;                 p += alup((size_t)N_NODES * 4);        // 200 KB
    int* bucketCount  = (int*)p;             p += alup((size_t)NBUCK * 4);
    int* bucketBase   = (int*)p;             p += alup((size_t)(NBUCK + 1) * 4);
    int* bucketCursor = (int*)p;             p += alup((size_t)NBUCK * 4);
    int* spk      = (int*)p;                 p += alup((size_t)N_EDGES * 4);        // 3.2 MB

    detect_kernel<<<1, 256, 0, stream>>>(h, flag);
    prep_kernel<<<(PREP_H + PREP_R + PREP_W + 255) / 256, 256, 0, stream>>>(
        h, r, norm, W, Wmsg, hx, r_bf, wt, flag);

    hipMemsetAsync(bucketCount, 0, (size_t)NBUCK * 4, stream);
    coarse_hist<<<128, 256, 0, stream>>>(dst, bucketCount);
    bucket_scan<<<1, 256, 0, stream>>>(bucketCount, bucketBase, bucketCursor);
    fill_lds<<<(N_EDGES + EPB - 1) / EPB, 512, 0, stream>>>(dst, src, rel, bucketCursor, spk);
    node_sort<<<NBUCK, 256, 0, stream>>>(bucketBase, spk, cursor);

    gather_kernel<<<(N_NODES * 16 + 255) / 256, 256, 0, stream>>>(hx, r_bf, norm, cursor, spk, flag);
    mfma_gemm<<<(N_NODES + GN - 1) / GN, 256, 0, stream>>>(hx, wt, b, d_out, flag);
}